// Round 1
// baseline (7186.509 us; speedup 1.0000x reference)
//
#include <hip/hip_runtime.h>
#include <cstddef>

// RQ-VAE forward. N=16384, D_IN=2048, H=4096, C=256, K=256. All f32.
// Encoder must stay f32-precise: the VQ argmin (threshold 2% of 255 on the
// index itself) cannot tolerate bf16-level error in ze_1.

#define NN 16384
#define DIN 2048
#define HH 4096
#define CC 256

// ---------------- f32 tiled GEMM: C = act(A@B + bias) ----------------
// A [M,K] row-major, B [K,N] row-major. BM=BN=128, BK=16, 256 threads,
// 8x8 micro-tile per thread. EPI: 0=none, 1=relu, 2=sigmoid.
template<int EPI>
__launch_bounds__(256)
__global__ void gemm_f32(const float* __restrict__ A, const float* __restrict__ B,
                         const float* __restrict__ bias, float* __restrict__ C,
                         int M, int N, int K)
{
    __shared__ float As[16][132];   // transposed A tile: As[k][m], pad avoids conflicts
    __shared__ float Bs[16][132];

    const int t  = threadIdx.x;
    const int tx = t & 15;          // 8-col group
    const int ty = t >> 4;          // 8-row group
    const int bm = blockIdx.y * 128;
    const int bn = blockIdx.x * 128;

    // A staging: thread -> (row ar, k-cols ac..ac+3), two rows (ar, ar+64)
    const int ar  = t >> 2;
    const int ac  = (t & 3) << 2;
    // B staging: thread -> (k-row bkr, cols bc..bc+3), two k-rows
    const int bkr = t >> 5;
    const int bc  = (t & 31) << 2;

    const float* Ap0 = A + (size_t)(bm + ar)      * K + ac;
    const float* Ap1 = A + (size_t)(bm + ar + 64) * K + ac;
    const float* Bp0 = B + (size_t)bkr       * N + bn + bc;
    const float* Bp1 = B + (size_t)(bkr + 8) * N + bn + bc;

    float acc[8][8] = {};

    for (int k0 = 0; k0 < K; k0 += 16) {
        float4 a0 = *(const float4*)(Ap0 + k0);
        float4 a1 = *(const float4*)(Ap1 + k0);
        float4 b0 = *(const float4*)(Bp0 + (size_t)k0 * N);
        float4 b1 = *(const float4*)(Bp1 + (size_t)k0 * N);
        __syncthreads();            // protect previous iter's LDS reads
        As[ac+0][ar] = a0.x; As[ac+1][ar] = a0.y;
        As[ac+2][ar] = a0.z; As[ac+3][ar] = a0.w;
        As[ac+0][ar+64] = a1.x; As[ac+1][ar+64] = a1.y;
        As[ac+2][ar+64] = a1.z; As[ac+3][ar+64] = a1.w;
        *(float4*)&Bs[bkr][bc]   = b0;
        *(float4*)&Bs[bkr+8][bc] = b1;
        __syncthreads();
        #pragma unroll
        for (int k = 0; k < 16; ++k) {
            float4 xa0 = *(const float4*)&As[k][ty*8];
            float4 xa1 = *(const float4*)&As[k][ty*8+4];
            float4 xb0 = *(const float4*)&Bs[k][tx*8];
            float4 xb1 = *(const float4*)&Bs[k][tx*8+4];
            float av[8] = {xa0.x,xa0.y,xa0.z,xa0.w,xa1.x,xa1.y,xa1.z,xa1.w};
            float bv[8] = {xb0.x,xb0.y,xb0.z,xb0.w,xb1.x,xb1.y,xb1.z,xb1.w};
            #pragma unroll
            for (int i = 0; i < 8; ++i)
                #pragma unroll
                for (int j = 0; j < 8; ++j)
                    acc[i][j] = fmaf(av[i], bv[j], acc[i][j]);
        }
    }

    float4 bb0 = *(const float4*)(bias + bn + tx*8);
    float4 bb1 = *(const float4*)(bias + bn + tx*8 + 4);
    float bcol[8] = {bb0.x,bb0.y,bb0.z,bb0.w,bb1.x,bb1.y,bb1.z,bb1.w};

    #pragma unroll
    for (int i = 0; i < 8; ++i) {
        const int row = bm + ty*8 + i;
        float o[8];
        #pragma unroll
        for (int j = 0; j < 8; ++j) {
            float v = acc[i][j] + bcol[j];
            if (EPI == 1) v = fmaxf(v, 0.0f);
            if (EPI == 2) v = 1.0f / (1.0f + expf(-v));
            o[j] = v;
        }
        float4 o0 = {o[0],o[1],o[2],o[3]};
        float4 o1 = {o[4],o[5],o[6],o[7]};
        float* cp = C + (size_t)row * N + bn + tx*8;
        *(float4*)cp       = o0;
        *(float4*)(cp + 4) = o1;
    }
}

// ---------------- VQ chain: 3 residual stages, 16 rows/block ----------------
__launch_bounds__(256)
__global__ void vq_kernel(const float* __restrict__ ze1,
                          const float* __restrict__ cb1,
                          const float* __restrict__ cb2,
                          const float* __restrict__ cb3,
                          float* __restrict__ out_ze2, float* __restrict__ out_ze3,
                          float* __restrict__ out_zq1, float* __restrict__ out_zq2,
                          float* __restrict__ out_zq3,
                          float* __restrict__ out_n1,  float* __restrict__ out_n2,
                          float* __restrict__ out_n3,
                          float* __restrict__ dec_in)
{
    __shared__ float Zs[16][260];    // current residual z (pad: stride%32==4)
    __shared__ float Ds[16][260];    // distances per (row, k)
    __shared__ float DecS[16][260];  // zq1+zq2+zq3 accumulator
    __shared__ float Srow[16];
    __shared__ int   Kmin[16];

    const int t    = threadIdx.x;
    const int row0 = blockIdx.x * 16;

    for (int i = t; i < 16*64; i += 256) {
        int r = i >> 6, c4 = (i & 63) << 2;
        float4 v = *(const float4*)(ze1 + (size_t)(row0 + r) * 256 + c4);
        *(float4*)&Zs[r][c4] = v;
        float4 z = {0.f,0.f,0.f,0.f};
        *(float4*)&DecS[r][c4] = z;
    }
    __syncthreads();

    const float* cbs[3] = {cb1, cb2, cb3};
    float* zqs[3] = {out_zq1, out_zq2, out_zq3};
    float* nss[3] = {out_n1, out_n2, out_n3};

    for (int s = 0; s < 3; ++s) {
        const float* cb = cbs[s];

        if (t < 16) {                           // row norms ||z||^2
            float ssum = 0.f;
            for (int c = 0; c < 256; ++c) ssum = fmaf(Zs[t][c], Zs[t][c], ssum);
            Srow[t] = ssum;
        }
        __syncthreads();

        {   // thread t owns codebook index k=t; dot against all 16 rows
            float accr[16];
            #pragma unroll
            for (int r = 0; r < 16; ++r) accr[r] = 0.f;
            float c2 = 0.f;
            const float* cbrow = cb + (size_t)t * 256;
            for (int c4 = 0; c4 < 256; c4 += 4) {
                float4 cv = *(const float4*)(cbrow + c4);
                c2 = fmaf(cv.x,cv.x,fmaf(cv.y,cv.y,fmaf(cv.z,cv.z,fmaf(cv.w,cv.w,c2))));
                #pragma unroll
                for (int r = 0; r < 16; ++r) {
                    float4 zv = *(const float4*)&Zs[r][c4];
                    accr[r] = fmaf(zv.x,cv.x,fmaf(zv.y,cv.y,
                              fmaf(zv.z,cv.z,fmaf(zv.w,cv.w,accr[r]))));
                }
            }
            // d = (S - 2*g) + c2, forced to np's elementwise f32 rounding grid
            #pragma unroll
            for (int r = 0; r < 16; ++r) {
                float g2 = __fmul_rn(2.0f, accr[r]);
                float t1 = __fsub_rn(Srow[r], g2);
                Ds[r][t]  = __fadd_rn(t1, c2);
            }
        }
        __syncthreads();

        if (t < 16) {                           // first-index argmin (np semantics)
            float best = Ds[t][0];
            int bk = 0;
            for (int k = 1; k < 256; ++k) {
                float v = Ds[t][k];
                if (v < best) { best = v; bk = k; }
            }
            Kmin[t] = bk;
            nss[s][row0 + t] = (float)bk;
        }
        __syncthreads();

        for (int i = t; i < 16*64; i += 256) {  // gather zq, residual, dec accum
            int r = i >> 6, c4 = (i & 63) << 2;
            const float* q = cb + (size_t)Kmin[r] * 256 + c4;
            float4 qv = *(const float4*)q;
            *(float4*)&zqs[s][(size_t)(row0 + r) * 256 + c4] = qv;
            float4 dv = *(float4*)&DecS[r][c4];
            dv.x = __fadd_rn(dv.x, qv.x); dv.y = __fadd_rn(dv.y, qv.y);
            dv.z = __fadd_rn(dv.z, qv.z); dv.w = __fadd_rn(dv.w, qv.w);
            *(float4*)&DecS[r][c4] = dv;
            if (s < 2) {
                float4 zv = *(float4*)&Zs[r][c4];
                zv.x = __fsub_rn(zv.x, qv.x); zv.y = __fsub_rn(zv.y, qv.y);
                zv.z = __fsub_rn(zv.z, qv.z); zv.w = __fsub_rn(zv.w, qv.w);
                *(float4*)&Zs[r][c4] = zv;
                float* oz = (s == 0) ? out_ze2 : out_ze3;
                *(float4*)&oz[(size_t)(row0 + r) * 256 + c4] = zv;
            }
        }
        __syncthreads();
    }

    // decoder_input = ze1 + ((zq1+zq2+zq3) - ze1), matching np op order
    for (int i = t; i < 16*64; i += 256) {
        int r = i >> 6, c4 = (i & 63) << 2;
        float4 z1 = *(const float4*)(ze1 + (size_t)(row0 + r) * 256 + c4);
        float4 dv = *(float4*)&DecS[r][c4];
        float4 o;
        o.x = __fadd_rn(z1.x, __fsub_rn(dv.x, z1.x));
        o.y = __fadd_rn(z1.y, __fsub_rn(dv.y, z1.y));
        o.z = __fadd_rn(z1.z, __fsub_rn(dv.z, z1.z));
        o.w = __fadd_rn(z1.w, __fsub_rn(dv.w, z1.w));
        *(float4*)&dec_in[(size_t)(row0 + r) * 256 + c4] = o;
    }
}

extern "C" void kernel_launch(void* const* d_in, const int* in_sizes, int n_in,
                              void* d_out, int out_size, void* d_ws, size_t ws_size,
                              hipStream_t stream)
{
    const float* x   = (const float*)d_in[0];
    const float* We1 = (const float*)d_in[1];
    const float* be1 = (const float*)d_in[2];
    const float* We2 = (const float*)d_in[3];
    const float* be2 = (const float*)d_in[4];
    const float* cb1 = (const float*)d_in[5];
    const float* cb2 = (const float*)d_in[6];
    const float* cb3 = (const float*)d_in[7];
    const float* Wd1 = (const float*)d_in[8];
    const float* bd1 = (const float*)d_in[9];
    const float* Wd2 = (const float*)d_in[10];
    const float* bd2 = (const float*)d_in[11];

    float* out  = (float*)d_out;
    float* x_hat = out;                    // 16384*2048
    float* ze1   = out + 33554432;         // 16384*256 each below
    float* ze2   = out + 37748736;
    float* ze3   = out + 41943040;
    float* zq1   = out + 46137344;
    float* zq2   = out + 50331648;
    float* zq3   = out + 54525952;
    float* n1    = out + 58720256;         // 16384 each
    float* n2    = out + 58736640;
    float* n3    = out + 58753024;

    float* ws  = (float*)d_ws;
    float* h1  = ws;                              // [16384,4096], reused as h2
    float* dec = ws + (size_t)16384 * 4096;       // [16384,256]

    dim3 blk(256);
    // ze_pre = relu(x @ W_e1 + b_e1)         [16384,4096] K=2048
    gemm_f32<1><<<dim3(HH/128, NN/128), blk, 0, stream>>>(x, We1, be1, h1, NN, HH, DIN);
    // ze_1 = h1 @ W_e2 + b_e2                [16384,256]  K=4096
    gemm_f32<0><<<dim3(CC/128, NN/128), blk, 0, stream>>>(h1, We2, be2, ze1, NN, CC, HH);
    // VQ chain
    vq_kernel<<<dim3(NN/16), blk, 0, stream>>>(ze1, cb1, cb2, cb3,
                                               ze2, ze3, zq1, zq2, zq3,
                                               n1, n2, n3, dec);
    // h2 = sigmoid(dec @ W_d1 + b_d1)        [16384,4096] K=256
    gemm_f32<2><<<dim3(HH/128, NN/128), blk, 0, stream>>>(dec, Wd1, bd1, h1, NN, HH, CC);
    // x_hat = h2 @ W_d2 + b_d2               [16384,2048] K=4096
    gemm_f32<0><<<dim3(DIN/128, NN/128), blk, 0, stream>>>(h1, Wd2, bd2, x_hat, NN, DIN, HH);
}

// Round 2
// 2538.299 us; speedup vs baseline: 2.8312x; 2.8312x over previous
//
#include <hip/hip_runtime.h>
#include <cstddef>

// RQ-VAE forward. N=16384, D_IN=2048, H=4096, C=256, K=256.
// Encoder GEMMs: bf16x3 split (hi/mid/lo) + 6 MFMA products == f32-grade
// precision (argmin indices must match np exactly). Decoder GEMMs: plain
// bf16 MFMA (x_hat compared at bf16 grid with loose threshold).

#define NN 16384
#define DIN 2048
#define HH 4096
#define CC 256

typedef __attribute__((ext_vector_type(8))) short bf16x8;
typedef __attribute__((ext_vector_type(4))) float f32x4;

__device__ inline unsigned short f2b(float v) {          // RNE f32 -> bf16 bits
    unsigned int u = __float_as_uint(v);
    return (unsigned short)((u + 0x7fffu + ((u >> 16) & 1u)) >> 16);
}
__device__ inline float b2f(unsigned short s) {
    return __uint_as_float(((unsigned int)s) << 16);
}

// ---------- weight transpose + split: W[K,N] f32 -> NP bf16 planes [N,K] ----
template<int NP>
__launch_bounds__(256)
__global__ void tsplit(const float* __restrict__ W,
                       unsigned short* __restrict__ T0,
                       unsigned short* __restrict__ T1,
                       unsigned short* __restrict__ T2,
                       int K, int N)
{
    __shared__ float tile[32][33];
    const int k0 = blockIdx.y * 32, n0 = blockIdx.x * 32;
    const int c = threadIdx.x & 31, r = threadIdx.x >> 5;
    #pragma unroll
    for (int i = 0; i < 4; ++i)
        tile[r + 8*i][c] = W[(size_t)(k0 + r + 8*i) * N + n0 + c];
    __syncthreads();
    #pragma unroll
    for (int i = 0; i < 4; ++i) {
        const int nl = r + 8*i, kl = c;
        float v = tile[kl][nl];
        size_t o = (size_t)(n0 + nl) * K + k0 + kl;
        unsigned short h = f2b(v);
        T0[o] = h;
        if (NP > 1) {
            float r1 = v - b2f(h);
            unsigned short m = f2b(r1);
            T1[o] = m;
            T2[o] = f2b(r1 - b2f(m));
        }
    }
}

// ---------- MFMA GEMM: C = act(A@B + bias), A f32 [M,K], B = NP bf16 planes
// [N,K] (pre-transposed). 128x128 tile, BK=32, 4 waves, 16x16x32 fragments.
// EPI: 0 none, 1 relu, 2 sigmoid. Output f32.
template<int NP, int EPI>
__launch_bounds__(256)
__global__ void gemm_sp(const float* __restrict__ A,
                        const unsigned short* __restrict__ B0,
                        const unsigned short* __restrict__ B1,
                        const unsigned short* __restrict__ B2,
                        const float* __restrict__ bias,
                        float* __restrict__ Cf,
                        int M, int N, int K)
{
    __shared__ unsigned short As[NP][128][32];
    __shared__ unsigned short Bs[NP][128][32];

    const int t    = threadIdx.x;
    const int wid  = t >> 6;
    const int lane = t & 63;
    const int bm   = blockIdx.y * 128;
    const int bn   = blockIdx.x * 128;
    const int wm   = (wid >> 1) * 64;
    const int wn   = (wid & 1) * 64;
    const int l15  = lane & 15;
    const int l4   = lane >> 4;          // 0..3

    f32x4 acc[4][4] = {};

    const unsigned short* Bp[3] = {B0, B1, B2};

    for (int k0 = 0; k0 < K; k0 += 32) {
        // ---- stage A (f32 -> split bf16 regs) ----
        float4 av[4];
        #pragma unroll
        for (int i = 0; i < 4; ++i) {
            const int chunk = t + i * 256;
            const int arow  = chunk >> 3;
            const int ac4   = (chunk & 7) << 2;
            av[i] = *(const float4*)(A + (size_t)(bm + arow) * K + k0 + ac4);
        }
        // ---- stage B (bf16 planes, 16B chunks) ----
        bf16x8 bv[NP][2];
        #pragma unroll
        for (int p = 0; p < NP; ++p)
            #pragma unroll
            for (int i = 0; i < 2; ++i) {
                const int chunk = t + i * 256;
                const int brow  = chunk >> 2;
                const int bc8   = (chunk & 3) << 3;
                bv[p][i] = *(const bf16x8*)(Bp[p] + (size_t)(bn + brow) * K + k0 + bc8);
            }

        __syncthreads();                 // previous iter's readers done

        #pragma unroll
        for (int i = 0; i < 4; ++i) {
            const int chunk = t + i * 256;
            const int arow  = chunk >> 3;
            const int ac4   = (chunk & 7) << 2;
            float vs[4] = {av[i].x, av[i].y, av[i].z, av[i].w};
            ushort4 hv, mv, lv;
            unsigned short* hp = (unsigned short*)&hv;
            unsigned short* mp = (unsigned short*)&mv;
            unsigned short* lp = (unsigned short*)&lv;
            #pragma unroll
            for (int j = 0; j < 4; ++j) {
                float v = vs[j];
                unsigned short h = f2b(v);
                hp[j] = h;
                if (NP > 1) {
                    float r1 = v - b2f(h);
                    unsigned short m = f2b(r1);
                    mp[j] = m;
                    lp[j] = f2b(r1 - b2f(m));
                }
            }
            *(ushort4*)&As[0][arow][ac4] = hv;
            if (NP > 1) {
                *(ushort4*)&As[1][arow][ac4] = mv;
                *(ushort4*)&As[2][arow][ac4] = lv;
            }
        }
        #pragma unroll
        for (int p = 0; p < NP; ++p)
            #pragma unroll
            for (int i = 0; i < 2; ++i) {
                const int chunk = t + i * 256;
                const int brow  = chunk >> 2;
                const int bc8   = (chunk & 3) << 3;
                *(bf16x8*)&Bs[p][brow][bc8] = bv[p][i];
            }

        __syncthreads();                 // tiles visible

        // ---- compute: 6 products (NP=3) or 1 (NP=1) ----
        const int nprod = (NP == 3) ? 6 : 1;
        const int pa[6] = {0, 0, 1, 0, 1, 2};
        const int pb[6] = {0, 1, 0, 2, 1, 0};
        #pragma unroll
        for (int q = 0; q < 6; ++q) {
            if (q >= nprod) break;
            const int ia = pa[q], ib = pb[q];
            bf16x8 af[4], bfr[4];
            #pragma unroll
            for (int mi = 0; mi < 4; ++mi)
                af[mi] = *(const bf16x8*)&As[ia][wm + mi*16 + l15][l4 * 8];
            #pragma unroll
            for (int ni = 0; ni < 4; ++ni)
                bfr[ni] = *(const bf16x8*)&Bs[ib][wn + ni*16 + l15][l4 * 8];
            #pragma unroll
            for (int mi = 0; mi < 4; ++mi)
                #pragma unroll
                for (int ni = 0; ni < 4; ++ni)
                    acc[mi][ni] = __builtin_amdgcn_mfma_f32_16x16x32_bf16(
                        af[mi], bfr[ni], acc[mi][ni], 0, 0, 0);
        }
    }

    // ---- epilogue: bias + activation + f32 store ----
    // C/D layout: col = lane&15, row = (lane>>4)*4 + reg  [m89/m91 verified]
    #pragma unroll
    for (int ni = 0; ni < 4; ++ni) {
        const int gcol = bn + wn + ni*16 + l15;
        const float bvv = bias[gcol];
        #pragma unroll
        for (int mi = 0; mi < 4; ++mi) {
            #pragma unroll
            for (int r = 0; r < 4; ++r) {
                float v = acc[mi][ni][r] + bvv;
                if (EPI == 1) v = fmaxf(v, 0.0f);
                if (EPI == 2) v = 1.0f / (1.0f + expf(-v));
                const int grow = bm + wm + mi*16 + l4*4 + r;
                Cf[(size_t)grow * N + gcol] = v;
            }
        }
    }
}

// ---------------- fallback f32 GEMM (round-1, used if ws too small) --------
template<int EPI>
__launch_bounds__(256)
__global__ void gemm_f32(const float* __restrict__ A, const float* __restrict__ B,
                         const float* __restrict__ bias, float* __restrict__ C,
                         int M, int N, int K)
{
    __shared__ float As[16][132];
    __shared__ float Bs[16][132];
    const int t  = threadIdx.x;
    const int tx = t & 15;
    const int ty = t >> 4;
    const int bm = blockIdx.y * 128;
    const int bn = blockIdx.x * 128;
    const int ar  = t >> 2;
    const int ac  = (t & 3) << 2;
    const int bkr = t >> 5;
    const int bc  = (t & 31) << 2;
    const float* Ap0 = A + (size_t)(bm + ar)      * K + ac;
    const float* Ap1 = A + (size_t)(bm + ar + 64) * K + ac;
    const float* Bp0 = B + (size_t)bkr       * N + bn + bc;
    const float* Bp1 = B + (size_t)(bkr + 8) * N + bn + bc;
    float acc[8][8] = {};
    for (int k0 = 0; k0 < K; k0 += 16) {
        float4 a0 = *(const float4*)(Ap0 + k0);
        float4 a1 = *(const float4*)(Ap1 + k0);
        float4 b0 = *(const float4*)(Bp0 + (size_t)k0 * N);
        float4 b1 = *(const float4*)(Bp1 + (size_t)k0 * N);
        __syncthreads();
        As[ac+0][ar] = a0.x; As[ac+1][ar] = a0.y;
        As[ac+2][ar] = a0.z; As[ac+3][ar] = a0.w;
        As[ac+0][ar+64] = a1.x; As[ac+1][ar+64] = a1.y;
        As[ac+2][ar+64] = a1.z; As[ac+3][ar+64] = a1.w;
        *(float4*)&Bs[bkr][bc]   = b0;
        *(float4*)&Bs[bkr+8][bc] = b1;
        __syncthreads();
        #pragma unroll
        for (int k = 0; k < 16; ++k) {
            float4 xa0 = *(const float4*)&As[k][ty*8];
            float4 xa1 = *(const float4*)&As[k][ty*8+4];
            float4 xb0 = *(const float4*)&Bs[k][tx*8];
            float4 xb1 = *(const float4*)&Bs[k][tx*8+4];
            float avr[8] = {xa0.x,xa0.y,xa0.z,xa0.w,xa1.x,xa1.y,xa1.z,xa1.w};
            float bvr[8] = {xb0.x,xb0.y,xb0.z,xb0.w,xb1.x,xb1.y,xb1.z,xb1.w};
            #pragma unroll
            for (int i = 0; i < 8; ++i)
                #pragma unroll
                for (int j = 0; j < 8; ++j)
                    acc[i][j] = fmaf(avr[i], bvr[j], acc[i][j]);
        }
    }
    float4 bb0 = *(const float4*)(bias + bn + tx*8);
    float4 bb1 = *(const float4*)(bias + bn + tx*8 + 4);
    float bcol[8] = {bb0.x,bb0.y,bb0.z,bb0.w,bb1.x,bb1.y,bb1.z,bb1.w};
    #pragma unroll
    for (int i = 0; i < 8; ++i) {
        const int row = bm + ty*8 + i;
        float o[8];
        #pragma unroll
        for (int j = 0; j < 8; ++j) {
            float v = acc[i][j] + bcol[j];
            if (EPI == 1) v = fmaxf(v, 0.0f);
            if (EPI == 2) v = 1.0f / (1.0f + expf(-v));
            o[j] = v;
        }
        float4 o0 = {o[0],o[1],o[2],o[3]};
        float4 o1 = {o[4],o[5],o[6],o[7]};
        float* cp = C + (size_t)row * N + bn + tx*8;
        *(float4*)cp       = o0;
        *(float4*)(cp + 4) = o1;
    }
}

// ---------------- VQ chain: 3 residual stages, 16 rows/block ----------------
__launch_bounds__(256)
__global__ void vq_kernel(const float* __restrict__ ze1,
                          const float* __restrict__ cb1,
                          const float* __restrict__ cb2,
                          const float* __restrict__ cb3,
                          float* __restrict__ out_ze2, float* __restrict__ out_ze3,
                          float* __restrict__ out_zq1, float* __restrict__ out_zq2,
                          float* __restrict__ out_zq3,
                          float* __restrict__ out_n1,  float* __restrict__ out_n2,
                          float* __restrict__ out_n3,
                          float* __restrict__ dec_in)
{
    __shared__ float Zs[16][260];
    __shared__ float Ds[16][260];
    __shared__ float DecS[16][260];
    __shared__ float Srow[16];
    __shared__ int   Kmin[16];

    const int t    = threadIdx.x;
    const int row0 = blockIdx.x * 16;

    for (int i = t; i < 16*64; i += 256) {
        int r = i >> 6, c4 = (i & 63) << 2;
        float4 v = *(const float4*)(ze1 + (size_t)(row0 + r) * 256 + c4);
        *(float4*)&Zs[r][c4] = v;
        float4 z = {0.f,0.f,0.f,0.f};
        *(float4*)&DecS[r][c4] = z;
    }
    __syncthreads();

    const float* cbs[3] = {cb1, cb2, cb3};
    float* zqs[3] = {out_zq1, out_zq2, out_zq3};
    float* nss[3] = {out_n1, out_n2, out_n3};

    for (int s = 0; s < 3; ++s) {
        const float* cb = cbs[s];
        if (t < 16) {
            float ssum = 0.f;
            for (int c = 0; c < 256; ++c) ssum = fmaf(Zs[t][c], Zs[t][c], ssum);
            Srow[t] = ssum;
        }
        __syncthreads();
        {
            float accr[16];
            #pragma unroll
            for (int r = 0; r < 16; ++r) accr[r] = 0.f;
            float c2 = 0.f;
            const float* cbrow = cb + (size_t)t * 256;
            for (int c4 = 0; c4 < 256; c4 += 4) {
                float4 cv = *(const float4*)(cbrow + c4);
                c2 = fmaf(cv.x,cv.x,fmaf(cv.y,cv.y,fmaf(cv.z,cv.z,fmaf(cv.w,cv.w,c2))));
                #pragma unroll
                for (int r = 0; r < 16; ++r) {
                    float4 zv = *(const float4*)&Zs[r][c4];
                    accr[r] = fmaf(zv.x,cv.x,fmaf(zv.y,cv.y,
                              fmaf(zv.z,cv.z,fmaf(zv.w,cv.w,accr[r]))));
                }
            }
            #pragma unroll
            for (int r = 0; r < 16; ++r) {
                float g2 = __fmul_rn(2.0f, accr[r]);
                float t1 = __fsub_rn(Srow[r], g2);
                Ds[r][t]  = __fadd_rn(t1, c2);
            }
        }
        __syncthreads();
        if (t < 16) {
            float best = Ds[t][0];
            int bk = 0;
            for (int k = 1; k < 256; ++k) {
                float v = Ds[t][k];
                if (v < best) { best = v; bk = k; }
            }
            Kmin[t] = bk;
            nss[s][row0 + t] = (float)bk;
        }
        __syncthreads();
        for (int i = t; i < 16*64; i += 256) {
            int r = i >> 6, c4 = (i & 63) << 2;
            const float* q = cb + (size_t)Kmin[r] * 256 + c4;
            float4 qv = *(const float4*)q;
            *(float4*)&zqs[s][(size_t)(row0 + r) * 256 + c4] = qv;
            float4 dv = *(float4*)&DecS[r][c4];
            dv.x = __fadd_rn(dv.x, qv.x); dv.y = __fadd_rn(dv.y, qv.y);
            dv.z = __fadd_rn(dv.z, qv.z); dv.w = __fadd_rn(dv.w, qv.w);
            *(float4*)&DecS[r][c4] = dv;
            if (s < 2) {
                float4 zv = *(float4*)&Zs[r][c4];
                zv.x = __fsub_rn(zv.x, qv.x); zv.y = __fsub_rn(zv.y, qv.y);
                zv.z = __fsub_rn(zv.z, qv.z); zv.w = __fsub_rn(zv.w, qv.w);
                *(float4*)&Zs[r][c4] = zv;
                float* oz = (s == 0) ? out_ze2 : out_ze3;
                *(float4*)&oz[(size_t)(row0 + r) * 256 + c4] = zv;
            }
        }
        __syncthreads();
    }

    for (int i = t; i < 16*64; i += 256) {
        int r = i >> 6, c4 = (i & 63) << 2;
        float4 z1 = *(const float4*)(ze1 + (size_t)(row0 + r) * 256 + c4);
        float4 dv = *(float4*)&DecS[r][c4];
        float4 o;
        o.x = __fadd_rn(z1.x, __fsub_rn(dv.x, z1.x));
        o.y = __fadd_rn(z1.y, __fsub_rn(dv.y, z1.y));
        o.z = __fadd_rn(z1.z, __fsub_rn(dv.z, z1.z));
        o.w = __fadd_rn(z1.w, __fsub_rn(dv.w, z1.w));
        *(float4*)&dec_in[(size_t)(row0 + r) * 256 + c4] = o;
    }
}

extern "C" void kernel_launch(void* const* d_in, const int* in_sizes, int n_in,
                              void* d_out, int out_size, void* d_ws, size_t ws_size,
                              hipStream_t stream)
{
    const float* x   = (const float*)d_in[0];
    const float* We1 = (const float*)d_in[1];
    const float* be1 = (const float*)d_in[2];
    const float* We2 = (const float*)d_in[3];
    const float* be2 = (const float*)d_in[4];
    const float* cb1 = (const float*)d_in[5];
    const float* cb2 = (const float*)d_in[6];
    const float* cb3 = (const float*)d_in[7];
    const float* Wd1 = (const float*)d_in[8];
    const float* bd1 = (const float*)d_in[9];
    const float* Wd2 = (const float*)d_in[10];
    const float* bd2 = (const float*)d_in[11];

    float* out   = (float*)d_out;
    float* x_hat = out;
    float* ze1   = out + 33554432;
    float* ze2   = out + 37748736;
    float* ze3   = out + 41943040;
    float* zq1   = out + 46137344;
    float* zq2   = out + 50331648;
    float* zq3   = out + 54525952;
    float* n1    = out + 58720256;
    float* n2    = out + 58736640;
    float* n3    = out + 58753024;

    // ---- workspace layout (new path): 360,710,144 B ----
    float* h   = (float*)d_ws;                          // [16384,4096] f32 (h, then h2)
    float* dec = h + (size_t)NN * HH;                   // [16384,256] f32
    unsigned short* We1t = (unsigned short*)(dec + (size_t)NN * CC);
    size_t szWe1 = (size_t)HH * DIN;                    // 8388608 el/plane
    unsigned short* We2t = We1t + 3 * szWe1;
    size_t szWe2 = (size_t)CC * HH;                     // 1048576
    unsigned short* Wd1t = We2t + 3 * szWe2;
    size_t szWd1 = (size_t)HH * CC;
    unsigned short* Wd2t = Wd1t + szWd1;
    size_t szWd2 = (size_t)DIN * HH;
    size_t need = (size_t)((unsigned short*)(Wd2t + szWd2) - (unsigned short*)d_ws) * 2;

    dim3 blk(256);

    if (ws_size >= need) {
        // weight transpose+split (every launch; ~0.05 ms total)
        tsplit<3><<<dim3(HH/32, DIN/32), blk, 0, stream>>>(We1, We1t, We1t+szWe1, We1t+2*szWe1, DIN, HH);
        tsplit<3><<<dim3(CC/32, HH/32),  blk, 0, stream>>>(We2, We2t, We2t+szWe2, We2t+2*szWe2, HH, CC);
        tsplit<1><<<dim3(HH/32, CC/32),  blk, 0, stream>>>(Wd1, Wd1t, nullptr, nullptr, CC, HH);
        tsplit<1><<<dim3(DIN/32, HH/32), blk, 0, stream>>>(Wd2, Wd2t, nullptr, nullptr, HH, DIN);

        // h = relu(x @ W_e1 + b_e1)     M=16384 N=4096 K=2048, 6-product split
        gemm_sp<3,1><<<dim3(HH/128, NN/128), blk, 0, stream>>>(x, We1t, We1t+szWe1, We1t+2*szWe1, be1, h, NN, HH, DIN);
        // ze1 = h @ W_e2 + b_e2         M=16384 N=256 K=4096, 6-product split
        gemm_sp<3,0><<<dim3(CC/128, NN/128), blk, 0, stream>>>(h, We2t, We2t+szWe2, We2t+2*szWe2, be2, ze1, NN, CC, HH);
        // VQ chain (f32, exact argmin semantics)
        vq_kernel<<<dim3(NN/16), blk, 0, stream>>>(ze1, cb1, cb2, cb3,
                                                   ze2, ze3, zq1, zq2, zq3,
                                                   n1, n2, n3, dec);
        // h2 = sigmoid(dec @ W_d1 + b_d1)  M=16384 N=4096 K=256, plain bf16
        gemm_sp<1,2><<<dim3(HH/128, NN/128), blk, 0, stream>>>(dec, Wd1t, nullptr, nullptr, bd1, h, NN, HH, CC);
        // x_hat = h2 @ W_d2 + b_d2         M=16384 N=2048 K=4096, plain bf16
        gemm_sp<1,0><<<dim3(DIN/128, NN/128), blk, 0, stream>>>(h, Wd2t, nullptr, nullptr, bd2, x_hat, NN, DIN, HH);
    } else {
        // fallback: round-1 all-f32 path (needs 285 MB)
        float* h1  = (float*)d_ws;
        float* dcf = h1 + (size_t)NN * HH;
        gemm_f32<1><<<dim3(HH/128, NN/128), blk, 0, stream>>>(x, We1, be1, h1, NN, HH, DIN);
        gemm_f32<0><<<dim3(CC/128, NN/128), blk, 0, stream>>>(h1, We2, be2, ze1, NN, CC, HH);
        vq_kernel<<<dim3(NN/16), blk, 0, stream>>>(ze1, cb1, cb2, cb3,
                                                   ze2, ze3, zq1, zq2, zq3,
                                                   n1, n2, n3, dcf);
        gemm_f32<2><<<dim3(HH/128, NN/128), blk, 0, stream>>>(dcf, Wd1, bd1, h1, NN, HH, CC);
        gemm_f32<0><<<dim3(DIN/128, NN/128), blk, 0, stream>>>(h1, Wd2, bd2, x_hat, NN, DIN, HH);
    }
}